// Round 12
// baseline (219.405 us; speedup 1.0000x reference)
//
#include <hip/hip_runtime.h>
#include <math.h>

#define Bn 16
#define Hh 512
#define Ww 512
#define HW_ (Hh * Ww)
#define TW 32                // output tile width (per wave)
#define WROWS 2              // output rows per wave
#define WPB 4                // waves per block (no interaction between them)
#define NTHREADS 256
#define SI 36                // input & feat grid col stride
#define SIN_E 256            // input entries per wave (216 valid + overreach pad)
#define NFE 144              // feat entries per 8-ch half per wave (4 rows x 36)
#define WAVE_LDS (SIN_E * 16 + 2 * NFE * 16)     // 4096 + 4608 = 8704
#define SMEM_BYTES (WPB * WAVE_LDS)              // 34816 -> 4 blocks/CU

typedef __bf16 bfrag __attribute__((ext_vector_type(8)));
typedef __bf16 bf4   __attribute__((ext_vector_type(4)));
typedef float  ffrag __attribute__((ext_vector_type(16)));
typedef float  f32x4 __attribute__((ext_vector_type(4)));
typedef float  f32x2 __attribute__((ext_vector_type(2)));

__device__ __forceinline__ short f2bf(float f) {           // RNE fp32 -> bf16 bits
    unsigned u = __float_as_uint(f);
    unsigned r = u + 0x7FFFu + ((u >> 16) & 1u);
    return (short)(r >> 16);
}

__device__ __forceinline__ f32x2 mk2(float a, float b) { f32x2 t; t.x = a; t.y = b; return t; }

// gelu exact-form via trans-free erf polynomial (same numerics as R3..R11)
__device__ __forceinline__ f32x2 gelu_fast2(f32x2 x) {
    const float C0 = 1.1259890f, C1 = -0.3565430f, C2 = 0.0848830f,
                C3 = -0.0110610f, C4 = 0.0005820f;
    f32x2 y = x * 0.70710678f;
    f32x2 t;
    t.x = fminf(fmaxf(y.x, -2.5f), 2.5f);
    t.y = fminf(fmaxf(y.y, -2.5f), 2.5f);
    f32x2 u = t * t;
    f32x2 p = u * C4 + C3;
    p = p * u + C2;
    p = p * u + C1;
    p = p * u + C0;
    f32x2 e = t * p;                 // ~erf(y)
    f32x2 h = x * 0.5f;
    return h * e + h;                // 0.5x(1+erf)
}

__device__ __forceinline__ float bilin(const float* __restrict__ img, float py, float px) {
    float y0f = floorf(py), x0f = floorf(px);
    float wy = py - y0f, wx = px - x0f;
    int y0 = (int)y0f, x0 = (int)x0f;
    int yc0 = min(max(y0, 0), Hh - 1), yc1 = min(max(y0 + 1, 0), Hh - 1);
    int xc0 = min(max(x0, 0), Ww - 1), xc1 = min(max(x0 + 1, 0), Ww - 1);
    bool vy0 = (unsigned)y0 < (unsigned)Hh, vy1 = (unsigned)(y0 + 1) < (unsigned)Hh;
    bool vx0 = (unsigned)x0 < (unsigned)Ww, vx1 = (unsigned)(x0 + 1) < (unsigned)Ww;
    const float* r0 = img + yc0 * Ww;
    const float* r1 = img + yc1 * Ww;
    float v00 = (vy0 && vx0) ? r0[xc0] : 0.0f;
    float v01 = (vy0 && vx1) ? r0[xc1] : 0.0f;
    float v10 = (vy1 && vx0) ? r1[xc0] : 0.0f;
    float v11 = (vy1 && vx1) ? r1[xc1] : 0.0f;
    return (1.0f - wy) * ((1.0f - wx) * v00 + wx * v01) +
           wy          * ((1.0f - wx) * v10 + wx * v11);
}

// ---- pre-pass: pack w2 A-frags (9 taps, 32x32x16) + w1 A-frags (2, 16x16x32) ----
// (layouts identical to R11; stride-independent)
__global__ void pack_w(const float* __restrict__ w2, const float* __restrict__ w1,
                       const float* __restrict__ b1, int* __restrict__ ws) {
    const int lane = threadIdx.x;            // 64 threads
    const int l31  = lane & 31;
    const int lh   = lane >> 5;
    for (int tap = 0; tap < 9; ++tap) {
        int pk[4];
        #pragma unroll
        for (int jj = 0; jj < 4; ++jj) {
            float v0 = (l31 < 18) ? w2[(l31 * 16 + lh * 8 + 2 * jj    ) * 9 + tap] : 0.0f;
            float v1 = (l31 < 18) ? w2[(l31 * 16 + lh * 8 + 2 * jj + 1) * 9 + tap] : 0.0f;
            pk[jj] = ((int)(unsigned short)f2bf(v0)) | ((int)f2bf(v1) << 16);
        }
        ((int4*)ws)[tap * 64 + lane] = make_int4(pk[0], pk[1], pk[2], pk[3]);
    }
    const int m  = lane & 15;
    const int kq = lane >> 4;
    for (int t = 0; t < 2; ++t) {
        int pk[4];
        #pragma unroll
        for (int jj = 0; jj < 4; ++jj) {
            float vv[2];
            #pragma unroll
            for (int h = 0; h < 2; ++h) {
                int k   = kq * 8 + 2 * jj + h;
                int kyl = k >> 4, kx = (k >> 2) & 3, c = k & 3;
                int ky  = 2 * t + kyl;
                float x = 0.0f;
                if (kx < 3 && c < 3 && ky < 3) x = w1[m * 27 + c * 9 + ky * 3 + kx];
                if (t == 0 && k == 3) x = b1[m];     // bias slot (reads const-1.0 channel)
                vv[h] = x;
            }
            pk[jj] = ((int)(unsigned short)f2bf(vv[0])) | ((int)f2bf(vv[1]) << 16);
        }
        ((int4*)ws)[576 + t * 64 + lane] = make_int4(pk[0], pk[1], pk[2], pk[3]);
    }
}

// Barrier-free kernel: each wave owns a 32x2 output tile and a private LDS slice.
// No s_barrier anywhere -- all LDS hazards are within-wave (compiler lgkmcnt).
__global__ __launch_bounds__(NTHREADS, 4) void residual_advection_fused(
    const float* __restrict__ pm25,   // (16,1,512,512)
    const float* __restrict__ wind,   // (16,2,512,512)
    const float* __restrict__ topo,   // (16,1,512,512)
    const float* __restrict__ b2,     // (18)
    const float* __restrict__ wt,     // (9)
    const int*   __restrict__ wsB,    // packed w2 + w1 A-fragments
    float* __restrict__ out)          // (16,1,512,512)
{
    __shared__ __align__(16) char smem[SMEM_BYTES];

    const int tid  = threadIdx.x;
    const int lane = tid & 63;
    const int wv   = tid >> 6;       // 0..3 (independent waves)
    const int l31  = lane & 31;
    const int lh   = lane >> 5;

    const int bb = blockIdx.z;
    const int x0 = blockIdx.x * TW;
    const int yb = blockIdx.y * (WPB * WROWS) + 2 * wv;   // wave's first output row

    __bf16* s_in   = (__bf16*)(smem + wv * WAVE_LDS);
    __bf16* s_feat = (__bf16*)(smem + wv * WAVE_LDS + SIN_E * 16);

    const bfrag* WF = (const bfrag*)wsB;
    bfrag w1f0 = WF[576 + lane];
    bfrag w1f1 = WF[640 + lane];

    const float* wp0 = wind + (bb * 2 + 0) * HW_;
    const float* wp1 = wind + (bb * 2 + 1) * HW_;
    const float* tp  = topo + bb * HW_;
    const float* img = pm25 + bb * HW_;

    // edge: any input row/col or feat mask can fall outside the image
    const bool edge = (yb < 2) || (yb > Hh - 4) || (x0 == 0) || (x0 == Ww - TW);

    // ---- P1 (per-wave): stage 6x36 input halo, dup-entry layout ----
    // input grid: row i = image yb-2+i (i<6), col j = image x0-2+j (stride SI=36).
    // entries 216..255 (r>=6) zero-filled: conv1's ky=3 zero-weight row reads them
    // (MFMA 0*NaN=NaN). Entry p: low 8B = pos p, high 8B = pos p+1.
    #pragma unroll
    for (int k = 0; k < 4; ++k) {
        const int p = lane + 64 * k;
        const int r = p / SI, c = p - r * SI;
        float c0 = 0.0f, c1 = 0.0f, c2 = 0.0f;
        if (r < 6) {
            int gy = yb - 2 + r, gx = x0 - 2 + c;
            if (!edge || ((unsigned)gy < (unsigned)Hh && (unsigned)gx < (unsigned)Ww)) {
                int g = gy * Ww + gx;
                c0 = wp0[g]; c1 = wp1[g]; c2 = tp[g];
            }
        }
        bf4 v;
        v[0] = (__bf16)c0; v[1] = (__bf16)c1; v[2] = (__bf16)c2; v[3] = (__bf16)1.0f;
        *(bf4*)&s_in[p * 8] = v;                       // entry p, low 8B
        if (p > 0) *(bf4*)&s_in[p * 8 - 4] = v;        // entry p-1, high 8B
    }

    // ---- P2 (per-wave): conv1 via MFMA 16x16x32, 9 tiles cover feat 4x36 ----
    // feat pos p = r*36+c (flat); input frag base = same p (grids share stride).
    {
        const int n    = lane & 15;
        const int kq   = lane >> 4;
        const int qoff = (kq >> 1) * SI + (kq & 1) * 2;
        #pragma unroll 3
        for (int t = 0; t < 9; ++t) {
            const int p = t * 16 + n;                   // 0..143
            f32x4 acc;
            acc[0] = 0.0f; acc[1] = 0.0f; acc[2] = 0.0f; acc[3] = 0.0f;
            bfrag bx0 = *(const bfrag*)&s_in[(p + qoff) * 8];           // ky 0,1
            bfrag bx1 = *(const bfrag*)&s_in[(p + qoff + 2 * SI) * 8];  // ky 2,(pad)
            acc = __builtin_amdgcn_mfma_f32_16x16x32_bf16(w1f0, bx0, acc, 0, 0, 0);
            acc = __builtin_amdgcn_mfma_f32_16x16x32_bf16(w1f1, bx1, acc, 0, 0, 0);
            f32x2 g0 = gelu_fast2(mk2(acc[0], acc[1]));
            f32x2 g1 = gelu_fast2(mk2(acc[2], acc[3]));
            if (edge) {                                 // conv2 zero-padding mask
                int fy = p / SI;
                int fx = p - fy * SI;
                int gy = yb - 1 + fy, gx = x0 - 1 + fx;
                float msk = ((unsigned)gy < (unsigned)Hh && (unsigned)gx < (unsigned)Ww)
                            ? 1.0f : 0.0f;
                g0 *= msk; g1 *= msk;
            }
            bf4 w4;
            w4[0] = (__bf16)g0.x; w4[1] = (__bf16)g0.y;
            w4[2] = (__bf16)g1.x; w4[3] = (__bf16)g1.y;
            *(bf4*)&s_feat[((kq >> 1) * NFE + p) * 8 + (kq & 1) * 4] = w4;
        }
    }

    // ---- P3 (per-wave): conv2 via MFMA 32x32x16, 12 shared feat frags ----
    // a0 = output row yb (feat rows 0-2), a1 = row yb+1 (rows 1-3); w2 in regs
    // (single-shot kernel: no loop -> no LICM/spill trap).
    ffrag a0, a1;
    #pragma unroll
    for (int r = 0; r < 16; ++r) { a0[r] = 0.0f; a1[r] = 0.0f; }
    {
        const int vb = (lh * NFE + l31) * 8;
        #pragma unroll
        for (int kx = 0; kx < 3; ++kx) {
            bfrag f0 = *(const bfrag*)&s_feat[vb + (0 * SI + kx) * 8];
            bfrag f1 = *(const bfrag*)&s_feat[vb + (1 * SI + kx) * 8];
            bfrag f2 = *(const bfrag*)&s_feat[vb + (2 * SI + kx) * 8];
            bfrag f3 = *(const bfrag*)&s_feat[vb + (3 * SI + kx) * 8];
            bfrag w0  = WF[(0 * 3 + kx) * 64 + lane];
            bfrag w1_ = WF[(1 * 3 + kx) * 64 + lane];
            bfrag w2_ = WF[(2 * 3 + kx) * 64 + lane];
            a0 = __builtin_amdgcn_mfma_f32_32x32x16_bf16(w0,  f0, a0, 0, 0, 0);
            a1 = __builtin_amdgcn_mfma_f32_32x32x16_bf16(w0,  f1, a1, 0, 0, 0);
            a0 = __builtin_amdgcn_mfma_f32_32x32x16_bf16(w1_, f1, a0, 0, 0, 0);
            a1 = __builtin_amdgcn_mfma_f32_32x32x16_bf16(w1_, f2, a1, 0, 0, 0);
            a0 = __builtin_amdgcn_mfma_f32_32x32x16_bf16(w2_, f2, a0, 0, 0, 0);
            a1 = __builtin_amdgcn_mfma_f32_32x32x16_bf16(w2_, f3, a1, 0, 0, 0);
        }
    }

    // ---- P4: lazy per-active-tap exchange, one bilinear sample per lane ----
    // C/D: col = pixel = l31, row = co = (reg&3)+8*(reg>>2)+4*lh.
    // Tap t rows (2t,2t+1) both live in half (t>>1)&1 at regs rg,rg+1.
    {
        const int py_i = yb + lh;
        const int px_i = x0 + l31;
        const float fy = (float)py_i, fx = (float)px_i;
        float o = 0.0f;
        #pragma unroll
        for (int t = 0; t < 9; ++t) {
            float wk = wt[t];                        // uniform -> scalar branch
            if (wk != 0.0f) {
                const int o_h = (t >> 1) & 1;                  // owner lane-half
                const int rg  = ((2 * t) & 3) + 4 * (t >> 2);  // dy reg; dx = rg+1
                float dy, dx;
                if (o_h == 0) {
                    float sy = __shfl_xor(a1[rg], 32);
                    float sx = __shfl_xor(a1[rg + 1], 32);
                    dy = lh ? sy : a0[rg];
                    dx = lh ? sx : a0[rg + 1];
                } else {
                    float sy = __shfl_xor(a0[rg], 32);
                    float sx = __shfl_xor(a0[rg + 1], 32);
                    dy = lh ? a1[rg] : sy;
                    dx = lh ? a1[rg + 1] : sx;
                }
                dy += b2[2 * t];
                dx += b2[2 * t + 1];
                float py = fy + (float)(t / 3 - 1) + dy;
                float px = fx + (float)(t % 3 - 1) + dx;
                o += wk * bilin(img, py, px);
            }
        }
        out[bb * HW_ + py_i * Ww + px_i] = o;
    }
}

extern "C" void kernel_launch(void* const* d_in, const int* in_sizes, int n_in,
                              void* d_out, int out_size, void* d_ws, size_t ws_size,
                              hipStream_t stream) {
    const float* pm25 = (const float*)d_in[0];
    const float* wind = (const float*)d_in[1];
    const float* topo = (const float*)d_in[2];
    const float* w1   = (const float*)d_in[3];
    const float* b1   = (const float*)d_in[4];
    const float* w2   = (const float*)d_in[5];
    const float* b2   = (const float*)d_in[6];
    const float* wt   = (const float*)d_in[7];
    float* o          = (float*)d_out;
    int*   wsB        = (int*)d_ws;   // 576+128 int4 = 11264 B

    pack_w<<<dim3(1), dim3(64), 0, stream>>>(w2, w1, b1, wsB);

    dim3 grid(Ww / TW, Hh / (WPB * WROWS), Bn);   // 16 x 64 x 16 = 16384 blocks
    residual_advection_fused<<<grid, dim3(NTHREADS), 0, stream>>>(
        pm25, wind, topo, b2, wt, wsB, o);
}

// Round 13
// 175.100 us; speedup vs baseline: 1.2530x; 1.2530x over previous
//
#include <hip/hip_runtime.h>
#include <math.h>

#define Bn 16
#define Hh 512
#define Ww 512
#define HW_ (Hh * Ww)
#define TW 32                // tile width
#define TH 16                // tile height
#define NTHREADS 512
#define S 37                 // unified grid stride (input halo & feat grids)
#define NROWS 20             // input halo rows (TH+4)
#define SIN_N 800            // staged entries: 20*37=740 valid + pad rows for ky3 reads
#define NFP 672              // feat positions per 8-ch half (42 tiles * 16)
#define NT 42                // conv1 position tiles of 16 (covers 18 rows * 37 cols)
#define SMEM_BYTES (SIN_N * 16 + 2 * NFP * 16)   // 34304 -> 4 blocks/CU

// raw barrier: LDS-visibility only (lgkmcnt drains ds ops; vmcnt stays in flight).
// Both inter-wave hazards in this kernel are LDS-only (s_in, s_feat), so the
// __syncthreads() vmcnt(0) drain is unnecessary serialization (R9/R11-verified).
#define BAR() do { \
    asm volatile("s_waitcnt lgkmcnt(0)" ::: "memory"); \
    __builtin_amdgcn_s_barrier(); \
    __builtin_amdgcn_sched_barrier(0); \
} while (0)

typedef __bf16 bfrag __attribute__((ext_vector_type(8)));
typedef __bf16 bf4   __attribute__((ext_vector_type(4)));
typedef float  ffrag __attribute__((ext_vector_type(16)));
typedef float  f32x4 __attribute__((ext_vector_type(4)));
typedef float  f32x2 __attribute__((ext_vector_type(2)));

__device__ __forceinline__ short f2bf(float f) {           // RNE fp32 -> bf16 bits
    unsigned u = __float_as_uint(f);
    unsigned r = u + 0x7FFFu + ((u >> 16) & 1u);
    return (short)(r >> 16);
}

__device__ __forceinline__ f32x2 mk2(float a, float b) { f32x2 t; t.x = a; t.y = b; return t; }

// gelu exact-form via trans-free erf polynomial (same numerics as R3..R12)
__device__ __forceinline__ f32x2 gelu_fast2(f32x2 x) {
    const float C0 = 1.1259890f, C1 = -0.3565430f, C2 = 0.0848830f,
                C3 = -0.0110610f, C4 = 0.0005820f;
    f32x2 y = x * 0.70710678f;
    f32x2 t;
    t.x = fminf(fmaxf(y.x, -2.5f), 2.5f);
    t.y = fminf(fmaxf(y.y, -2.5f), 2.5f);
    f32x2 u = t * t;
    f32x2 p = u * C4 + C3;
    p = p * u + C2;
    p = p * u + C1;
    p = p * u + C0;
    f32x2 e = t * p;                 // ~erf(y)
    f32x2 h = x * 0.5f;
    return h * e + h;                // 0.5x(1+erf)
}

__device__ __forceinline__ float bilin(const float* __restrict__ img, float py, float px) {
    float y0f = floorf(py), x0f = floorf(px);
    float wy = py - y0f, wx = px - x0f;
    int y0 = (int)y0f, x0 = (int)x0f;
    int yc0 = min(max(y0, 0), Hh - 1), yc1 = min(max(y0 + 1, 0), Hh - 1);
    int xc0 = min(max(x0, 0), Ww - 1), xc1 = min(max(x0 + 1, 0), Ww - 1);
    bool vy0 = (unsigned)y0 < (unsigned)Hh, vy1 = (unsigned)(y0 + 1) < (unsigned)Hh;
    bool vx0 = (unsigned)x0 < (unsigned)Ww, vx1 = (unsigned)(x0 + 1) < (unsigned)Ww;
    const float* r0 = img + yc0 * Ww;
    const float* r1 = img + yc1 * Ww;
    float v00 = (vy0 && vx0) ? r0[xc0] : 0.0f;
    float v01 = (vy0 && vx1) ? r0[xc1] : 0.0f;
    float v10 = (vy1 && vx0) ? r1[xc0] : 0.0f;
    float v11 = (vy1 && vx1) ? r1[xc1] : 0.0f;
    return (1.0f - wy) * ((1.0f - wx) * v00 + wx * v01) +
           wy          * ((1.0f - wx) * v10 + wx * v11);
}

// ---- pre-pass: pack w2 A-frags (9 taps, 32x32x16) + w1 A-frags (2, 16x16x32) ----
// ws int4 [0,576)   : w2 frags: lane l31=co(m), elem j -> ci = lh*8+j, per tap
// ws int4 [576,704) : w1 frags: lane m=lane&15(co), k=(lane>>4)*8+j,
//                     k = 16*kyloc + 4*kx + c, ky = 2*t + kyloc;
//                     value = w1[co][c][ky][kx] (kx<3,c<3,ky<3); slot t=0,k=3 = b1[co]
__global__ void pack_w(const float* __restrict__ w2, const float* __restrict__ w1,
                       const float* __restrict__ b1, int* __restrict__ ws) {
    const int lane = threadIdx.x;            // 64 threads
    const int l31  = lane & 31;
    const int lh   = lane >> 5;
    for (int tap = 0; tap < 9; ++tap) {
        int pk[4];
        #pragma unroll
        for (int jj = 0; jj < 4; ++jj) {
            float v0 = (l31 < 18) ? w2[(l31 * 16 + lh * 8 + 2 * jj    ) * 9 + tap] : 0.0f;
            float v1 = (l31 < 18) ? w2[(l31 * 16 + lh * 8 + 2 * jj + 1) * 9 + tap] : 0.0f;
            pk[jj] = ((int)(unsigned short)f2bf(v0)) | ((int)f2bf(v1) << 16);
        }
        ((int4*)ws)[tap * 64 + lane] = make_int4(pk[0], pk[1], pk[2], pk[3]);
    }
    const int m  = lane & 15;
    const int kq = lane >> 4;
    for (int t = 0; t < 2; ++t) {
        int pk[4];
        #pragma unroll
        for (int jj = 0; jj < 4; ++jj) {
            float vv[2];
            #pragma unroll
            for (int h = 0; h < 2; ++h) {
                int k   = kq * 8 + 2 * jj + h;
                int kyl = k >> 4, kx = (k >> 2) & 3, c = k & 3;
                int ky  = 2 * t + kyl;
                float x = 0.0f;
                if (kx < 3 && c < 3 && ky < 3) x = w1[m * 27 + c * 9 + ky * 3 + kx];
                if (t == 0 && k == 3) x = b1[m];     // bias slot (reads const-1.0 channel)
                vv[h] = x;
            }
            pk[jj] = ((int)(unsigned short)f2bf(vv[0])) | ((int)f2bf(vv[1]) << 16);
        }
        ((int4*)ws)[576 + t * 64 + lane] = make_int4(pk[0], pk[1], pk[2], pk[3]);
    }
}

__global__ __launch_bounds__(NTHREADS, 8) void residual_advection_fused(
    const float* __restrict__ pm25,   // (16,1,512,512)
    const float* __restrict__ wind,   // (16,2,512,512)
    const float* __restrict__ topo,   // (16,1,512,512)
    const float* __restrict__ b2,     // (18)
    const float* __restrict__ wt,     // (9)
    const int*   __restrict__ wsB,    // packed w2 + w1 A-fragments
    float* __restrict__ out)          // (16,1,512,512)
{
    __shared__ __align__(16) char smem[SMEM_BYTES];
    __bf16* s_in   = (__bf16*)smem;                  // dup entries, 16B each
    __bf16* s_feat = (__bf16*)(smem + SIN_N * 16);   // [2][NFP][8]

    const int tid = threadIdx.x;
    const int bb  = blockIdx.z;
    const int ty0 = blockIdx.y * TH;
    const int tx0 = blockIdx.x * TW;
    const bool edge = (ty0 == 0) || (ty0 == Hh - TH) || (tx0 == 0) || (tx0 == Ww - TW);

    const int lane = tid & 63;
    const int wv   = tid >> 6;       // 0..7
    const int l31  = lane & 31;
    const int lh   = lane >> 5;

    const bfrag* WF = (const bfrag*)wsB;

    // hoist conv1 weight A-frags (L2-hot; latency hidden under staging)
    bfrag w1f0 = WF[576 + lane];
    bfrag w1f1 = WF[640 + lane];

    // ---- P1: stage input halo, dup layout: pos idx -> entry[idx].lo, entry[idx-1].hi ----
    for (int idx = tid; idx < SIN_N; idx += NTHREADS) {
        float c0 = 0.0f, c1 = 0.0f, c2 = 0.0f;
        if (idx < NROWS * S) {
            int r = idx / S, c = idx - r * S;
            if (!edge) {                              // interior: no bounds masks
                int g = (ty0 - 2 + r) * Ww + (tx0 - 2 + c);
                c0 = wind[(bb * 2 + 0) * HW_ + g];
                c1 = wind[(bb * 2 + 1) * HW_ + g];
                c2 = topo[bb * HW_ + g];
            } else {
                int gy = ty0 - 2 + r, gx = tx0 - 2 + c;
                if ((unsigned)gy < (unsigned)Hh && (unsigned)gx < (unsigned)Ww) {
                    int g = gy * Ww + gx;
                    c0 = wind[(bb * 2 + 0) * HW_ + g];
                    c1 = wind[(bb * 2 + 1) * HW_ + g];
                    c2 = topo[bb * HW_ + g];
                }
            }
        }
        bf4 v;
        v[0] = (__bf16)c0; v[1] = (__bf16)c1; v[2] = (__bf16)c2; v[3] = (__bf16)1.0f;
        *(bf4*)&s_in[idx * 8] = v;                       // entry idx, low 8B
        if (idx > 0) *(bf4*)&s_in[idx * 8 - 4] = v;      // entry idx-1, high 8B
    }
    BAR();                             // B1: s_in ready (LDS-only drain)

    // ---- P2: conv1 via MFMA 16x16x32, A=w1 (m=co16), B=input rows (n=pos) ----
    // K = 2 kernel-rows x (4 kx x 4 ch); bias via const-1.0 channel slot.
    // unroll 2: tile k+1's ds_reads issue under tile k's MFMA+gelu chain.
    {
        const int n    = lane & 15;
        const int kq   = lane >> 4;
        const int qoff = (kq >> 1) * S + (kq & 1) * 2;   // kyloc row + kx-pair offset
        #pragma unroll 2
        for (int tt = wv; tt < NT; tt += 8) {
            const int p = tt * 16 + n;
            f32x4 acc;
            acc[0] = 0.0f; acc[1] = 0.0f; acc[2] = 0.0f; acc[3] = 0.0f;
            bfrag bx0 = *(const bfrag*)&s_in[(p + qoff) * 8];           // ky rows 0,1
            bfrag bx1 = *(const bfrag*)&s_in[(p + qoff + 2 * S) * 8];   // ky rows 2,(pad)
            acc = __builtin_amdgcn_mfma_f32_16x16x32_bf16(w1f0, bx0, acc, 0, 0, 0);
            acc = __builtin_amdgcn_mfma_f32_16x16x32_bf16(w1f1, bx1, acc, 0, 0, 0);
            // epilogue: gelu + (edge-only) validity mask, bf16 store of 4 co values
            f32x2 g0 = gelu_fast2(mk2(acc[0], acc[1]));
            f32x2 g1 = gelu_fast2(mk2(acc[2], acc[3]));
            if (edge) {
                int fy = p / S;
                int fx = p - fy * S;
                int gy = ty0 + fy - 1, gx = tx0 + fx - 1;
                float msk = ((unsigned)gy < (unsigned)Hh && (unsigned)gx < (unsigned)Ww)
                            ? 1.0f : 0.0f;
                g0 *= msk; g1 *= msk;
            }
            bf4 w4;
            w4[0] = (__bf16)g0.x; w4[1] = (__bf16)g0.y;
            w4[2] = (__bf16)g1.x; w4[3] = (__bf16)g1.y;
            // co-group kq: half = kq>>1, sub-slot = kq&1
            *(bf4*)&s_feat[((kq >> 1) * NFP + p) * 8 + (kq & 1) * 4] = w4;
        }
    }
    BAR();                             // B2: s_feat ready (LDS-only drain)

    // ---- P3: conv2 via MFMA 32x32x16, A=w2 (m=co18), B=feat (n=pixel) ----
    // Fragment sharing: chain a1's (ky,kx) fragment == chain a0's (ky+1,kx);
    // 12 unique ds_read_b128 (4 rows x 3 kx) instead of 18.
    ffrag a0, a1;
    #pragma unroll
    for (int r = 0; r < 16; ++r) { a0[r] = 0.0f; a1[r] = 0.0f; }
    {
        const int vb = (lh * NFP + (2 * wv) * S + l31) * 8;
        #pragma unroll
        for (int kx = 0; kx < 3; ++kx) {
            bfrag f0 = *(const bfrag*)&s_feat[vb + (0 * S + kx) * 8];
            bfrag f1 = *(const bfrag*)&s_feat[vb + (1 * S + kx) * 8];
            bfrag f2 = *(const bfrag*)&s_feat[vb + (2 * S + kx) * 8];
            bfrag f3 = *(const bfrag*)&s_feat[vb + (3 * S + kx) * 8];
            bfrag w0 = WF[(0 * 3 + kx) * 64 + lane];
            bfrag w1_ = WF[(1 * 3 + kx) * 64 + lane];
            bfrag w2_ = WF[(2 * 3 + kx) * 64 + lane];
            a0 = __builtin_amdgcn_mfma_f32_32x32x16_bf16(w0,  f0, a0, 0, 0, 0);
            a1 = __builtin_amdgcn_mfma_f32_32x32x16_bf16(w0,  f1, a1, 0, 0, 0);
            a0 = __builtin_amdgcn_mfma_f32_32x32x16_bf16(w1_, f1, a0, 0, 0, 0);
            a1 = __builtin_amdgcn_mfma_f32_32x32x16_bf16(w1_, f2, a1, 0, 0, 0);
            a0 = __builtin_amdgcn_mfma_f32_32x32x16_bf16(w2_, f2, a0, 0, 0, 0);
            a1 = __builtin_amdgcn_mfma_f32_32x32x16_bf16(w2_, f3, a1, 0, 0, 0);
        }
    }

    // ---- P4: lazy per-active-tap exchange, one bilinear sample per lane ----
    // C/D: col = pixel = l31, row = co = (reg&3)+8*(reg>>2)+4*lh.
    // Tap t rows (2t,2t+1) both live in half o=(t>>1)&1 at regs rg,rg+1.
    // Chain a0 = pixel row 2wv, chain a1 = row 2wv+1; lane outputs row 2wv+lh.
    {
        const float* img = pm25 + bb * HW_;
        const int py_i = ty0 + 2 * wv + lh;
        const int px_i = tx0 + l31;
        const float fy = (float)py_i, fx = (float)px_i;
        float o = 0.0f;
        #pragma unroll
        for (int t = 0; t < 9; ++t) {
            float wk = wt[t];                        // uniform -> scalar branch
            if (wk != 0.0f) {
                const int o_h = (t >> 1) & 1;                  // owner lane-half
                const int rg  = ((2 * t) & 3) + 4 * (t >> 2);  // dy reg; dx = rg+1
                float dy, dx;
                if (o_h == 0) {
                    float sy = __shfl_xor(a1[rg], 32);
                    float sx = __shfl_xor(a1[rg + 1], 32);
                    dy = lh ? sy : a0[rg];
                    dx = lh ? sx : a0[rg + 1];
                } else {
                    float sy = __shfl_xor(a0[rg], 32);
                    float sx = __shfl_xor(a0[rg + 1], 32);
                    dy = lh ? a1[rg] : sy;
                    dx = lh ? a1[rg + 1] : sx;
                }
                dy += b2[2 * t];
                dx += b2[2 * t + 1];
                float py = fy + (float)(t / 3 - 1) + dy;
                float px = fx + (float)(t % 3 - 1) + dx;
                o += wk * bilin(img, py, px);
            }
        }
        out[bb * HW_ + py_i * Ww + px_i] = o;
    }
}

extern "C" void kernel_launch(void* const* d_in, const int* in_sizes, int n_in,
                              void* d_out, int out_size, void* d_ws, size_t ws_size,
                              hipStream_t stream) {
    const float* pm25 = (const float*)d_in[0];
    const float* wind = (const float*)d_in[1];
    const float* topo = (const float*)d_in[2];
    const float* w1   = (const float*)d_in[3];
    const float* b1   = (const float*)d_in[4];
    const float* w2   = (const float*)d_in[5];
    const float* b2   = (const float*)d_in[6];
    const float* wt   = (const float*)d_in[7];
    float* o          = (float*)d_out;
    int*   wsB        = (int*)d_ws;   // 576+128 int4 = 11264 B

    pack_w<<<dim3(1), dim3(64), 0, stream>>>(w2, w1, b1, wsB);

    dim3 grid(Ww / TW, Hh / TH, Bn);   // 16 x 32 x 16 = 8192 blocks, 4/CU resident
    residual_advection_fused<<<grid, dim3(NTHREADS), 0, stream>>>(
        pm25, wind, topo, b2, wt, wsB, o);
}